// Round 11
// baseline (248.764 us; speedup 1.0000x reference)
//
#include <hip/hip_runtime.h>
#include <hip/hip_fp16.h>
#include <hip/hip_cooperative_groups.h>
#include <cstdint>
#include <cstddef>
#include <math.h>

namespace cg = cooperative_groups;

// Problem constants (from reference)
#define NNODES 20000
#define NEDGES 320000
#define TDIM   8
#define CDIM   32
#define RROWS  (NNODES * TDIM)           // 160000 rows of 32 floats (= 2500*64)
#define NELEM  (RROWS * CDIM)            // 5,120,000 elements

#define CSR_GRID 256
#define CSR_GT   (CSR_GRID * 256)

static __device__ __forceinline__ unsigned pk2(float a, float b) {
    __half2 h = __floats2half2_rn(a, b);
    return *reinterpret_cast<unsigned*>(&h);
}

// convert 8 packed halves (uint4) to 8 floats
static __device__ __forceinline__ void cvt8(uint4 r, float* a) {
    float2 f;
    f = __half22float2(*reinterpret_cast<__half2*>(&r.x)); a[0] = f.x; a[1] = f.y;
    f = __half22float2(*reinterpret_cast<__half2*>(&r.y)); a[2] = f.x; a[3] = f.y;
    f = __half22float2(*reinterpret_cast<__half2*>(&r.z)); a[4] = f.x; a[5] = f.y;
    f = __half22float2(*reinterpret_cast<__half2*>(&r.w)); a[6] = f.x; a[7] = f.y;
}

// ---------------------------------------------------------------------------
// Cooperative CSR build + WU precompute: ONE dispatch (was 7).
// Phases separated by grid.sync():
//   0: zero counts (blocks 0-78) + WU1/WU2 = W@U (blocks 0-7)
//   1: histogram of targets (all 65536 threads, stride loop)
//   2: per-block sums of counts -> bsum[79]
//   3: block base = sum(bsum[<blk]) + local scan -> offsets, cursor
//   4: scatter src indices into CSR slots (atomic cursor)
// ---------------------------------------------------------------------------
__global__ __launch_bounds__(256) void csrwu_kernel(
    const int* __restrict__ ei,
    const float* __restrict__ Wn1, const float* __restrict__ u1, float* __restrict__ WU1,
    const float* __restrict__ Wn2, const float* __restrict__ u2, float* __restrict__ WU2,
    int* __restrict__ counts, int* __restrict__ offsets, int* __restrict__ cursor,
    int* __restrict__ bsum, int* __restrict__ csr)
{
    cg::grid_group grid = cg::this_grid();
    int blk = blockIdx.x, tid = threadIdx.x;
    int gtid = blk * 256 + tid;
    __shared__ int sd[256];

    // ---- phase 0 ----
    if (gtid < NNODES) counts[gtid] = 0;
    if (blk < 8) {
        const float* W  = (blk < 4) ? Wn1 : Wn2;
        const float* U  = (blk < 4) ? u1  : u2;
        float*       WU = (blk < 4) ? WU1 : WU2;
        int idx = (blk & 3) * 256 + tid;
        int k = idx >> 5, c = idx & 31;
        float acc = 0.f;
#pragma unroll
        for (int j = 0; j < CDIM; ++j) acc = fmaf(W[k * CDIM + j], U[j * CDIM + c], acc);
        WU[idx] = acc;
    }
    grid.sync();

    // ---- phase 1: hist ----
    for (int e = gtid; e < NEDGES; e += CSR_GT)
        atomicAdd(&counts[ei[NEDGES + e]], 1);
    grid.sync();

    // ---- phase 2: block sums ----
    int v = 0;
    if (blk < 79) {
        v = (gtid < NNODES) ? counts[gtid] : 0;
        sd[tid] = v;
        __syncthreads();
#pragma unroll
        for (int off = 128; off > 0; off >>= 1) {
            if (tid < off) sd[tid] += sd[tid + off];
            __syncthreads();
        }
        if (tid == 0) bsum[blk] = sd[0];
    }
    grid.sync();

    // ---- phase 3: base + local scan ----
    if (blk < 79) {
        sd[tid] = (tid < blk) ? bsum[tid] : 0;   // blk<=78 -> valid bsum indices
        __syncthreads();
#pragma unroll
        for (int off = 128; off > 0; off >>= 1) {
            if (tid < off) sd[tid] += sd[tid + off];
            __syncthreads();
        }
        int base = sd[0];
        __syncthreads();
        sd[tid] = v;
        __syncthreads();
#pragma unroll
        for (int off = 1; off < 256; off <<= 1) {
            int t = (tid >= off) ? sd[tid - off] : 0;
            __syncthreads();
            sd[tid] += t;
            __syncthreads();
        }
        int excl = base + sd[tid] - v;
        if (gtid < NNODES) { offsets[gtid] = excl; cursor[gtid] = excl; }
        if (gtid == NNODES - 1) offsets[NNODES] = NEDGES;
    }
    grid.sync();

    // ---- phase 4: scatter ----
    for (int e = gtid; e < NEDGES; e += CSR_GT) {
        int t = ei[NEDGES + e];
        int pos = atomicAdd(&cursor[t], 1);
        csr[pos] = ei[e];
    }
}

// ---------------------------------------------------------------------------
// Fused linear kernel: h = x @ W ; hu16 = half(x @ WU).  (R9 geometry:
// thread = (row, chunk-of-8), 4 waves x 64 rows/block, 2500 blocks.)
// ---------------------------------------------------------------------------
__global__ __launch_bounds__(256) void linear2_kernel(
    const float* __restrict__ in,   // [RROWS, 32]
    const float* __restrict__ W,    // [32, 32]
    const float* __restrict__ WU,   // [32, 32] = W@U precomputed
    float* __restrict__ h,          // [RROWS, 32] f32
    __half* __restrict__ hu16)      // [RROWS, 32] fp16
{
    __shared__ float sx[64][33];
    int tid = threadIdx.x;
    int rowBase = blockIdx.x * 64;

    const float4* in4 = (const float4*)(in + (size_t)rowBase * CDIM);
#pragma unroll
    for (int i = 0; i < 2; ++i) {
        int idx = tid + i * 256;            // 0..511
        float4 v = in4[idx];
        int r = idx >> 3, q = idx & 7;
        sx[r][4 * q + 0] = v.x; sx[r][4 * q + 1] = v.y;
        sx[r][4 * q + 2] = v.z; sx[r][4 * q + 3] = v.w;
    }
    __syncthreads();

    int lane  = tid & 63;
    int chunk = __builtin_amdgcn_readfirstlane(tid >> 6);   // 0..3, SGPR
    int row = rowBase + lane;

    float hr[8], acc[8];
#pragma unroll
    for (int j = 0; j < 8; ++j) { hr[j] = 0.f; acc[j] = 0.f; }

    const float* Wc  = W  + chunk * 8;      // uniform -> s_load
    const float* WUc = WU + chunk * 8;      // uniform -> s_load
#pragma unroll 4
    for (int k = 0; k < CDIM; ++k) {
        float xk = sx[lane][k];             // ds_read_b32
#pragma unroll
        for (int j = 0; j < 8; ++j) {
            hr[j]  = fmaf(xk, Wc[k * CDIM + j],  hr[j]);
            acc[j] = fmaf(xk, WUc[k * CDIM + j], acc[j]);
        }
    }

    float* hp = h + (size_t)row * CDIM + chunk * 8;
    ((float4*)hp)[0] = make_float4(hr[0], hr[1], hr[2], hr[3]);
    ((float4*)hp)[1] = make_float4(hr[4], hr[5], hr[6], hr[7]);

    uint4* up = (uint4*)((char*)hu16 + (size_t)row * 64 + chunk * 16);
    *up = make_uint4(pk2(acc[0], acc[1]), pk2(acc[2], acc[3]),
                     pk2(acc[4], acc[5]), pk2(acc[6], acc[7]));
}

// ---------------------------------------------------------------------------
// Aggregation: one wave per node, TWO edges per wave.
// Half-wave (32 lanes) owns one edge; lane = (tau = l32>>2, li = l32&3) holds
// 8 channels as one uint4 (16B).  Dot = 8 FMA + 2-step shfl in the 4-lane tau
// group.  2 slots unrolled -> 4 edges in flight/wave; next indices prefetched.
// Cross-half max combine via shfl_xor(.,32) at the end; lanes 0-31 write the
// fused leaky_relu(h+agg) row.  `h`/`out` may alias per-thread.
// ---------------------------------------------------------------------------
__global__ __launch_bounds__(256) void agg_kernel(
    const int* __restrict__ offsets,
    const int* __restrict__ csr_src,
    const __half* __restrict__ hu16, // gather source [RROWS,32] fp16
    const float* h,                  // [RROWS,32]
    float* out)                      // [RROWS,32]
{
    int tid = threadIdx.x;
    int n = blockIdx.x * 4 + (tid >> 6);     // node for this wave
    int l64 = tid & 63;
    int half = l64 >> 5;                     // edge slot parity
    int l32 = l64 & 31;
    uint32_t rowOff = (uint32_t)l32 * 16u;   // byte off in 512B fp16 row
    const char* hub = (const char*)hu16;

    float b[8];
    cvt8(*(const uint4*)(hub + ((uint32_t)n << 9) + rowOff), b);  // x_i

    int k0 = offsets[n];
    int k1 = offsets[n + 1];

    float m[8];
#pragma unroll
    for (int j = 0; j < 8; ++j) m[j] = -INFINITY;

    int k = k0;
    int e0 = 0, e1 = 0;
    if (k + 4 <= k1) {
        e0 = csr_src[k + half];
        e1 = csr_src[k + 2 + half];
    }
    while (k + 4 <= k1) {
        uint4 r0 = *(const uint4*)(hub + (((uint32_t)e0 << 9) + rowOff));
        uint4 r1 = *(const uint4*)(hub + (((uint32_t)e1 << 9) + rowOff));
        k += 4;
        if (k + 4 <= k1) {                   // prefetch next indices
            e0 = csr_src[k + half];
            e1 = csr_src[k + 2 + half];
        }
        float a0[8], a1[8];
        cvt8(r0, a0); cvt8(r1, a1);
        float q0 = 0.f, q1 = 0.f;
#pragma unroll
        for (int j = 0; j < 8; ++j) { q0 = fmaf(a0[j], b[j], q0); q1 = fmaf(a1[j], b[j], q1); }
        q0 += __shfl_xor(q0, 1); q1 += __shfl_xor(q1, 1);
        q0 += __shfl_xor(q0, 2); q1 += __shfl_xor(q1, 2);
        float g0 = 1.f / (1.f + __expf(-q0));
        float g1 = 1.f / (1.f + __expf(-q1));
#pragma unroll
        for (int j = 0; j < 8; ++j) {
            m[j] = fmaxf(m[j], a0[j] * g0);
            m[j] = fmaxf(m[j], a1[j] * g1);
        }
    }
    // tail (<4 edges): both halves process the same edge (idempotent max)
    for (; k < k1; ++k) {
        int s = csr_src[k];
        float a0[8];
        cvt8(*(const uint4*)(hub + (((uint32_t)s << 9) + rowOff)), a0);
        float q0 = 0.f;
#pragma unroll
        for (int j = 0; j < 8; ++j) q0 = fmaf(a0[j], b[j], q0);
        q0 += __shfl_xor(q0, 1);
        q0 += __shfl_xor(q0, 2);
        float g0 = 1.f / (1.f + __expf(-q0));
#pragma unroll
        for (int j = 0; j < 8; ++j) m[j] = fmaxf(m[j], a0[j] * g0);
    }

    // combine the two halves' maxima
#pragma unroll
    for (int j = 0; j < 8; ++j) m[j] = fmaxf(m[j], __shfl_xor(m[j], 32));

    if (half == 0) {
        bool has = (k1 > k0);
        uint32_t nodeOff = (uint32_t)n * 1024u + (uint32_t)l32 * 32u;  // f32 row
        const char* hb = (const char*)h;
        float4 hv0 = *(const float4*)(hb + nodeOff);
        float4 hv1 = *(const float4*)(hb + nodeOff + 16);
        float o[8];
        float hvv[8] = {hv0.x, hv0.y, hv0.z, hv0.w, hv1.x, hv1.y, hv1.z, hv1.w};
#pragma unroll
        for (int j = 0; j < 8; ++j) {
            float a = has ? m[j] : 0.f;
            float vv = hvv[j] + a;
            o[j] = (vv >= 0.f) ? vv : 0.01f * vv;
        }
        char* ob = (char*)out;
        *(float4*)(ob + nodeOff)      = make_float4(o[0], o[1], o[2], o[3]);
        *(float4*)(ob + nodeOff + 16) = make_float4(o[4], o[5], o[6], o[7]);
    }
}

// ---------------------------------------------------------------------------
// Orchestration: 5 dispatches total (was 11).
// ws: [counts N][offsets N+1][cursor N][bsum 128][WU1 1024][WU2 1024]
//     [csr E][pad][A: NELEM f32][H16: NELEM half]
// Layer 1: linear2(X, Wn1, WU1)->h1=A, hu16->H16;  agg(H16, h=A)->c1=A
// Layer 2: linear2(A, Wn2, WU2)->h2=d_out, hu16->H16; agg(H16, h=d_out)->d_out
// ---------------------------------------------------------------------------
extern "C" void kernel_launch(void* const* d_in, const int* in_sizes, int n_in,
                              void* d_out, int out_size, void* d_ws, size_t ws_size,
                              hipStream_t stream)
{
    const int*   ei  = (const int*)  d_in[1];
    const float* X   = (const float*)d_in[0];
    // d_in[2]=edge_attr, d_in[4]=We1, d_in[7]=We2: dead code in reference
    const float* Wn1 = (const float*)d_in[3];
    const float* u1  = (const float*)d_in[5];
    const float* Wn2 = (const float*)d_in[6];
    const float* u2  = (const float*)d_in[8];

    float* out = (float*)d_out;

    int* counts  = (int*)d_ws;
    int* offsets = counts + NNODES;          // NNODES+1
    int* cursor  = offsets + NNODES + 1;
    int* bsum    = cursor + NNODES;          // 128
    float* WU1   = (float*)(bsum + 128);     // 1024
    float* WU2   = WU1 + 1024;               // 1024
    int* csr     = (int*)(WU2 + 1024);       // NEDGES
    float*  A   = (float*)(((uintptr_t)(csr + NEDGES) + 255) & ~(uintptr_t)255);
    __half* H16 = (__half*)(A + NELEM);

    const int linBlocks = RROWS / 64;        // 2500
    const int aggBlocks = NNODES / 4;        // 5000

    // ---- cooperative CSR + WU build (1 dispatch) ----
    void* args[] = {
        (void*)&ei,
        (void*)&Wn1, (void*)&u1, (void*)&WU1,
        (void*)&Wn2, (void*)&u2, (void*)&WU2,
        (void*)&counts, (void*)&offsets, (void*)&cursor,
        (void*)&bsum, (void*)&csr
    };
    hipLaunchCooperativeKernel((const void*)csrwu_kernel,
                               dim3(CSR_GRID), dim3(256), args, 0, stream);

    // ---- layer 1 ----
    linear2_kernel<<<linBlocks, 256, 0, stream>>>(X, Wn1, WU1, A, H16);
    agg_kernel<<<aggBlocks, 256, 0, stream>>>(offsets, csr, H16, A, A);

    // ---- layer 2 ----
    linear2_kernel<<<linBlocks, 256, 0, stream>>>(A, Wn2, WU2, out, H16);
    agg_kernel<<<aggBlocks, 256, 0, stream>>>(offsets, csr, H16, out, out);
}

// Round 12
// 145.889 us; speedup vs baseline: 1.7052x; 1.7052x over previous
//
#include <hip/hip_runtime.h>
#include <hip/hip_fp16.h>
#include <cstdint>
#include <cstddef>
#include <math.h>

// Problem constants (from reference)
#define NNODES 20000
#define NEDGES 320000
#define TDIM   8
#define CDIM   32
#define RROWS  (NNODES * TDIM)           // 160000 rows of 32 floats (= 2500*64)
#define NELEM  (RROWS * CDIM)            // 5,120,000 elements

static __device__ __forceinline__ unsigned pk2(float a, float b) {
    __half2 h = __floats2half2_rn(a, b);
    return *reinterpret_cast<unsigned*>(&h);
}

// convert 8 packed halves (uint4) to 8 floats
static __device__ __forceinline__ void cvt8(uint4 r, float* a) {
    float2 f;
    f = __half22float2(*reinterpret_cast<__half2*>(&r.x)); a[0] = f.x; a[1] = f.y;
    f = __half22float2(*reinterpret_cast<__half2*>(&r.y)); a[2] = f.x; a[3] = f.y;
    f = __half22float2(*reinterpret_cast<__half2*>(&r.z)); a[4] = f.x; a[5] = f.y;
    f = __half22float2(*reinterpret_cast<__half2*>(&r.w)); a[6] = f.x; a[7] = f.y;
}

// ---------------------------------------------------------------------------
// WU = W @ U for both layers in ONE launch (blockIdx selects layer).
// (R10 post-mortem: cooperative grid.sync costs ~25-30us each on MI355X --
// multi-kernel pipeline is strictly better here.  Reverted.)
// ---------------------------------------------------------------------------
__global__ __launch_bounds__(1024) void wu_kernel(
    const float* __restrict__ W1, const float* __restrict__ U1, float* __restrict__ WU1,
    const float* __restrict__ W2, const float* __restrict__ U2, float* __restrict__ WU2)
{
    const float* W  = blockIdx.x ? W2  : W1;
    const float* U  = blockIdx.x ? U2  : U1;
    float*       WU = blockIdx.x ? WU2 : WU1;
    int t = threadIdx.x;
    int k = t >> 5, c = t & 31;
    float acc = 0.f;
#pragma unroll
    for (int j = 0; j < CDIM; ++j) acc = fmaf(W[k * CDIM + j], U[j * CDIM + c], acc);
    WU[k * CDIM + c] = acc;
}

// ---------------------------------------------------------------------------
// Fused linear kernel: h = x @ W ; hu16 = half(x @ WU).  (R9 geometry:
// thread = (row, chunk-of-8), 4 waves x 64 rows/block, 2500 blocks.)
// ---------------------------------------------------------------------------
__global__ __launch_bounds__(256) void linear2_kernel(
    const float* __restrict__ in,   // [RROWS, 32]
    const float* __restrict__ W,    // [32, 32]
    const float* __restrict__ WU,   // [32, 32] = W@U precomputed
    float* __restrict__ h,          // [RROWS, 32] f32
    __half* __restrict__ hu16)      // [RROWS, 32] fp16
{
    __shared__ float sx[64][33];
    int tid = threadIdx.x;
    int rowBase = blockIdx.x * 64;

    const float4* in4 = (const float4*)(in + (size_t)rowBase * CDIM);
#pragma unroll
    for (int i = 0; i < 2; ++i) {
        int idx = tid + i * 256;            // 0..511
        float4 v = in4[idx];
        int r = idx >> 3, q = idx & 7;
        sx[r][4 * q + 0] = v.x; sx[r][4 * q + 1] = v.y;
        sx[r][4 * q + 2] = v.z; sx[r][4 * q + 3] = v.w;
    }
    __syncthreads();

    int lane  = tid & 63;
    int chunk = __builtin_amdgcn_readfirstlane(tid >> 6);   // 0..3, SGPR
    int row = rowBase + lane;

    float hr[8], acc[8];
#pragma unroll
    for (int j = 0; j < 8; ++j) { hr[j] = 0.f; acc[j] = 0.f; }

    const float* Wc  = W  + chunk * 8;      // uniform -> s_load
    const float* WUc = WU + chunk * 8;      // uniform -> s_load
#pragma unroll 4
    for (int k = 0; k < CDIM; ++k) {
        float xk = sx[lane][k];             // ds_read_b32
#pragma unroll
        for (int j = 0; j < 8; ++j) {
            hr[j]  = fmaf(xk, Wc[k * CDIM + j],  hr[j]);
            acc[j] = fmaf(xk, WUc[k * CDIM + j], acc[j]);
        }
    }

    float* hp = h + (size_t)row * CDIM + chunk * 8;
    ((float4*)hp)[0] = make_float4(hr[0], hr[1], hr[2], hr[3]);
    ((float4*)hp)[1] = make_float4(hr[4], hr[5], hr[6], hr[7]);

    uint4* up = (uint4*)((char*)hu16 + (size_t)row * 64 + chunk * 16);
    *up = make_uint4(pk2(acc[0], acc[1]), pk2(acc[2], acc[3]),
                     pk2(acc[4], acc[5]), pk2(acc[6], acc[7]));
}

// ---------------------------------------------------------------------------
// CSR build: hist -> 3-stage parallel scan -> scatter.  Once per launch.
// ---------------------------------------------------------------------------
__global__ __launch_bounds__(256) void zero_counts_kernel(int* __restrict__ counts)
{
    int i = blockIdx.x * 256 + threadIdx.x;
    if (i < NNODES) counts[i] = 0;
}

__global__ __launch_bounds__(256) void hist_kernel(
    const int* __restrict__ ei, int* __restrict__ counts)
{
    int e = blockIdx.x * 256 + threadIdx.x;
    if (e < NEDGES) atomicAdd(&counts[ei[NEDGES + e]], 1);
}

__global__ __launch_bounds__(256) void blocksum_kernel(
    const int* __restrict__ counts, int* __restrict__ bsum)
{
    __shared__ int sd[256];
    int tid = threadIdx.x;
    int i = blockIdx.x * 256 + tid;
    sd[tid] = (i < NNODES) ? counts[i] : 0;
    __syncthreads();
#pragma unroll
    for (int off = 128; off > 0; off >>= 1) {
        if (tid < off) sd[tid] += sd[tid + off];
        __syncthreads();
    }
    if (tid == 0) bsum[blockIdx.x] = sd[0];
}

__global__ __launch_bounds__(128) void bscan_kernel(
    const int* __restrict__ bsum, int* __restrict__ bbase, int nblocks)
{
    __shared__ int sd[128];
    int tid = threadIdx.x;
    int v = (tid < nblocks) ? bsum[tid] : 0;
    sd[tid] = v;
    __syncthreads();
#pragma unroll
    for (int off = 1; off < 128; off <<= 1) {
        int t = (tid >= off) ? sd[tid - off] : 0;
        __syncthreads();
        sd[tid] += t;
        __syncthreads();
    }
    if (tid < nblocks) bbase[tid] = sd[tid] - v;   // exclusive
}

__global__ __launch_bounds__(256) void localscan_kernel(
    const int* __restrict__ counts, const int* __restrict__ bbase,
    int* __restrict__ offsets, int* __restrict__ cursor)
{
    __shared__ int sd[256];
    int tid = threadIdx.x;
    int i = blockIdx.x * 256 + tid;
    int v = (i < NNODES) ? counts[i] : 0;
    sd[tid] = v;
    __syncthreads();
#pragma unroll
    for (int off = 1; off < 256; off <<= 1) {
        int t = (tid >= off) ? sd[tid - off] : 0;
        __syncthreads();
        sd[tid] += t;
        __syncthreads();
    }
    int excl = bbase[blockIdx.x] + sd[tid] - v;
    if (i < NNODES) { offsets[i] = excl; cursor[i] = excl; }
    if (i == NNODES - 1) offsets[NNODES] = NEDGES;
}

__global__ __launch_bounds__(256) void scatter_kernel(
    const int* __restrict__ ei,
    int* __restrict__ cursor,
    int* __restrict__ csr_src)
{
    int e = blockIdx.x * 256 + threadIdx.x;
    if (e < NEDGES) {
        int t = ei[NEDGES + e];
        int pos = atomicAdd(&cursor[t], 1);
        csr_src[pos] = ei[e];
    }
}

// ---------------------------------------------------------------------------
// Aggregation: one wave per node, TWO edges per wave (this round's change).
// Half-wave (32 lanes) owns one edge; lane holds 8 channels as one uint4
// (16B) -> one 512B fully-coalesced gather per half-wave.  Dot = 8 FMA +
// 2-step shfl in the 4-lane tau group.  2 slots unrolled -> 4 edges in
// flight/wave; next indices prefetched under row-load latency.  Cross-half
// max via shfl_xor(.,32); lanes 0-31 write leaky_relu(h+agg).
// ---------------------------------------------------------------------------
__global__ __launch_bounds__(256) void agg_kernel(
    const int* __restrict__ offsets,
    const int* __restrict__ csr_src,
    const __half* __restrict__ hu16, // gather source [RROWS,32] fp16
    const float* h,                  // [RROWS,32]
    float* out)                      // [RROWS,32]
{
    int tid = threadIdx.x;
    int n = blockIdx.x * 4 + (tid >> 6);     // node for this wave
    int l64 = tid & 63;
    int half = l64 >> 5;                     // edge slot parity
    int l32 = l64 & 31;
    uint32_t rowOff = (uint32_t)l32 * 16u;   // byte off in 512B fp16 row
    const char* hub = (const char*)hu16;

    float b[8];
    cvt8(*(const uint4*)(hub + ((uint32_t)n << 9) + rowOff), b);  // x_i

    int k0 = offsets[n];
    int k1 = offsets[n + 1];

    float m[8];
#pragma unroll
    for (int j = 0; j < 8; ++j) m[j] = -INFINITY;

    int k = k0;
    int e0 = 0, e1 = 0;
    if (k + 4 <= k1) {
        e0 = csr_src[k + half];
        e1 = csr_src[k + 2 + half];
    }
    while (k + 4 <= k1) {
        uint4 r0 = *(const uint4*)(hub + (((uint32_t)e0 << 9) + rowOff));
        uint4 r1 = *(const uint4*)(hub + (((uint32_t)e1 << 9) + rowOff));
        k += 4;
        if (k + 4 <= k1) {                   // prefetch next indices
            e0 = csr_src[k + half];
            e1 = csr_src[k + 2 + half];
        }
        float a0[8], a1[8];
        cvt8(r0, a0); cvt8(r1, a1);
        float q0 = 0.f, q1 = 0.f;
#pragma unroll
        for (int j = 0; j < 8; ++j) { q0 = fmaf(a0[j], b[j], q0); q1 = fmaf(a1[j], b[j], q1); }
        q0 += __shfl_xor(q0, 1); q1 += __shfl_xor(q1, 1);
        q0 += __shfl_xor(q0, 2); q1 += __shfl_xor(q1, 2);
        float g0 = 1.f / (1.f + __expf(-q0));
        float g1 = 1.f / (1.f + __expf(-q1));
#pragma unroll
        for (int j = 0; j < 8; ++j) {
            m[j] = fmaxf(m[j], a0[j] * g0);
            m[j] = fmaxf(m[j], a1[j] * g1);
        }
    }
    // tail (<4 edges): both halves process the same edge (idempotent max)
    for (; k < k1; ++k) {
        int s = csr_src[k];
        float a0[8];
        cvt8(*(const uint4*)(hub + (((uint32_t)s << 9) + rowOff)), a0);
        float q0 = 0.f;
#pragma unroll
        for (int j = 0; j < 8; ++j) q0 = fmaf(a0[j], b[j], q0);
        q0 += __shfl_xor(q0, 1);
        q0 += __shfl_xor(q0, 2);
        float g0 = 1.f / (1.f + __expf(-q0));
#pragma unroll
        for (int j = 0; j < 8; ++j) m[j] = fmaxf(m[j], a0[j] * g0);
    }

    // combine the two halves' maxima
#pragma unroll
    for (int j = 0; j < 8; ++j) m[j] = fmaxf(m[j], __shfl_xor(m[j], 32));

    if (half == 0) {
        bool has = (k1 > k0);
        uint32_t nodeOff = (uint32_t)n * 1024u + (uint32_t)l32 * 32u;  // f32 row
        const char* hb = (const char*)h;
        float4 hv0 = *(const float4*)(hb + nodeOff);
        float4 hv1 = *(const float4*)(hb + nodeOff + 16);
        float o[8];
        float hvv[8] = {hv0.x, hv0.y, hv0.z, hv0.w, hv1.x, hv1.y, hv1.z, hv1.w};
#pragma unroll
        for (int j = 0; j < 8; ++j) {
            float a = has ? m[j] : 0.f;
            float vv = hvv[j] + a;
            o[j] = (vv >= 0.f) ? vv : 0.01f * vv;
        }
        char* ob = (char*)out;
        *(float4*)(ob + nodeOff)      = make_float4(o[0], o[1], o[2], o[3]);
        *(float4*)(ob + nodeOff + 16) = make_float4(o[4], o[5], o[6], o[7]);
    }
}

// ---------------------------------------------------------------------------
// Orchestration (R10 structure + new agg).
// ws: [counts N][offsets N+1][cursor N][bsum 128][bbase 128][WU1 1024]
//     [WU2 1024][csr E][pad][A: NELEM f32][H16: NELEM half]
// Layer 1: linear2(X, Wn1, WU1)->h1=A, hu16->H16;  agg(H16, h=A)->c1=A
// Layer 2: linear2(A, Wn2, WU2)->h2=d_out, hu16->H16; agg(H16, h=d_out)->d_out
// ---------------------------------------------------------------------------
extern "C" void kernel_launch(void* const* d_in, const int* in_sizes, int n_in,
                              void* d_out, int out_size, void* d_ws, size_t ws_size,
                              hipStream_t stream)
{
    const float* X   = (const float*)d_in[0];
    const int*   ei  = (const int*)  d_in[1];
    // d_in[2]=edge_attr, d_in[4]=We1, d_in[7]=We2: dead code in reference
    const float* Wn1 = (const float*)d_in[3];
    const float* u1  = (const float*)d_in[5];
    const float* Wn2 = (const float*)d_in[6];
    const float* u2  = (const float*)d_in[8];

    float* out = (float*)d_out;

    int* counts  = (int*)d_ws;
    int* offsets = counts + NNODES;          // NNODES+1
    int* cursor  = offsets + NNODES + 1;
    int* bsum    = cursor + NNODES;          // 128
    int* bbase   = bsum + 128;               // 128
    float* WU1   = (float*)(bbase + 128);    // 1024
    float* WU2   = WU1 + 1024;               // 1024
    int* csr     = (int*)(WU2 + 1024);       // NEDGES
    float*  A   = (float*)(((uintptr_t)(csr + NEDGES) + 255) & ~(uintptr_t)255);
    __half* H16 = (__half*)(A + NELEM);

    const int linBlocks  = RROWS / 64;             // 2500
    const int edgeBlocks = (NEDGES + 255) / 256;   // 1250
    const int nodeBlocks = (NNODES + 255) / 256;   // 79
    const int aggBlocks  = NNODES / 4;             // 5000

    // ---- combined weights + CSR build (shared by both layers) ----
    wu_kernel<<<2, 1024, 0, stream>>>(Wn1, u1, WU1, Wn2, u2, WU2);
    zero_counts_kernel<<<nodeBlocks, 256, 0, stream>>>(counts);
    hist_kernel<<<edgeBlocks, 256, 0, stream>>>(ei, counts);
    blocksum_kernel<<<nodeBlocks, 256, 0, stream>>>(counts, bsum);
    bscan_kernel<<<1, 128, 0, stream>>>(bsum, bbase, nodeBlocks);
    localscan_kernel<<<nodeBlocks, 256, 0, stream>>>(counts, bbase, offsets, cursor);
    scatter_kernel<<<edgeBlocks, 256, 0, stream>>>(ei, cursor, csr);

    // ---- layer 1 ----
    linear2_kernel<<<linBlocks, 256, 0, stream>>>(X, Wn1, WU1, A, H16);
    agg_kernel<<<aggBlocks, 256, 0, stream>>>(offsets, csr, H16, A, A);

    // ---- layer 2 ----
    linear2_kernel<<<linBlocks, 256, 0, stream>>>(A, Wn2, WU2, out, H16);
    agg_kernel<<<aggBlocks, 256, 0, stream>>>(offsets, csr, H16, out, out);
}

// Round 13
// 144.981 us; speedup vs baseline: 1.7158x; 1.0063x over previous
//
#include <hip/hip_runtime.h>
#include <hip/hip_fp16.h>
#include <cstdint>
#include <cstddef>
#include <math.h>

// Problem constants (from reference)
#define NNODES 20000
#define NEDGES 320000
#define TDIM   8
#define CDIM   32
#define RROWS  (NNODES * TDIM)           // 160000 rows of 32 values (= 2500*64)
#define NELEM  (RROWS * CDIM)            // 5,120,000 elements
#define NODEB  79                        // ceil(NNODES/256)

static __device__ __forceinline__ unsigned pk2(float a, float b) {
    __half2 h = __floats2half2_rn(a, b);
    return *reinterpret_cast<unsigned*>(&h);
}

// convert 8 packed halves (uint4) to 8 floats
static __device__ __forceinline__ void cvt8(uint4 r, float* a) {
    float2 f;
    f = __half22float2(*reinterpret_cast<__half2*>(&r.x)); a[0] = f.x; a[1] = f.y;
    f = __half22float2(*reinterpret_cast<__half2*>(&r.y)); a[2] = f.x; a[3] = f.y;
    f = __half22float2(*reinterpret_cast<__half2*>(&r.z)); a[4] = f.x; a[5] = f.y;
    f = __half22float2(*reinterpret_cast<__half2*>(&r.w)); a[6] = f.x; a[7] = f.y;
}

// ---------------------------------------------------------------------------
// init: zero counts (blocks 0..78) + WU = W@U for both layers (blocks 79..86).
// Independent work -> one dispatch, no internal ordering needed.
// ---------------------------------------------------------------------------
__global__ __launch_bounds__(256) void init_kernel(
    const float* __restrict__ Wn1, const float* __restrict__ u1, float* __restrict__ WU1,
    const float* __restrict__ Wn2, const float* __restrict__ u2, float* __restrict__ WU2,
    int* __restrict__ counts)
{
    int blk = blockIdx.x, tid = threadIdx.x;
    if (blk < NODEB) {
        int i = blk * 256 + tid;
        if (i < NNODES) counts[i] = 0;
        return;
    }
    int b = blk - NODEB;                 // 0..7
    const float* W  = (b < 4) ? Wn1 : Wn2;
    const float* U  = (b < 4) ? u1  : u2;
    float*       WU = (b < 4) ? WU1 : WU2;
    int idx = (b & 3) * 256 + tid;       // 0..1023
    int k = idx >> 5, c = idx & 31;
    float acc = 0.f;
#pragma unroll
    for (int j = 0; j < CDIM; ++j) acc = fmaf(W[k * CDIM + j], U[j * CDIM + c], acc);
    WU[idx] = acc;
}

__global__ __launch_bounds__(256) void hist_kernel(
    const int* __restrict__ ei, int* __restrict__ counts)
{
    int e = blockIdx.x * 256 + threadIdx.x;
    if (e < NEDGES) atomicAdd(&counts[ei[NEDGES + e]], 1);
}

// ---------------------------------------------------------------------------
// Single-dispatch scan (was blocksum+bscan+localscan).  Each of the 79 blocks
// redundantly computes its prefix base by summing counts[0 .. blk*256)
// (coalesced, <=79 iters/thread, ~1us total) then does its local scan.
// ---------------------------------------------------------------------------
__global__ __launch_bounds__(256) void scan_kernel(
    const int* __restrict__ counts,
    int* __restrict__ offsets, int* __restrict__ cursor)
{
    __shared__ int sd[256];
    int blk = blockIdx.x, tid = threadIdx.x;

    // prefix base for this block
    int pre = 0;
    for (int i = tid; i < blk * 256; i += 256) pre += counts[i];
    sd[tid] = pre;
    __syncthreads();
#pragma unroll
    for (int off = 128; off > 0; off >>= 1) {
        if (tid < off) sd[tid] += sd[tid + off];
        __syncthreads();
    }
    int base = sd[0];
    __syncthreads();

    // local inclusive scan of this block's 256 counts
    int i = blk * 256 + tid;
    int v = (i < NNODES) ? counts[i] : 0;
    sd[tid] = v;
    __syncthreads();
#pragma unroll
    for (int off = 1; off < 256; off <<= 1) {
        int t = (tid >= off) ? sd[tid - off] : 0;
        __syncthreads();
        sd[tid] += t;
        __syncthreads();
    }
    int excl = base + sd[tid] - v;
    if (i < NNODES) { offsets[i] = excl; cursor[i] = excl; }
    if (i == NNODES - 1) offsets[NNODES] = NEDGES;
}

__global__ __launch_bounds__(256) void scatter_kernel(
    const int* __restrict__ ei,
    int* __restrict__ cursor,
    int* __restrict__ csr_src)
{
    int e = blockIdx.x * 256 + threadIdx.x;
    if (e < NEDGES) {
        int t = ei[NEDGES + e];
        int pos = atomicAdd(&cursor[t], 1);
        csr_src[pos] = ei[e];
    }
}

// ---------------------------------------------------------------------------
// Fused linear kernel: h16 = half(x @ W) ; hu16 = half(x @ WU).
// R9 geometry (thread = (row, chunk-of-8), 4 waves x 64 rows/block).
// IN16: input rows are fp16 (layer 2 reads c1 as fp16); else f32 (layer 1, X).
// Both outputs fp16 now (h consumed row-locally by agg; 5e-4 relerr OK).
// ---------------------------------------------------------------------------
template<bool IN16>
__global__ __launch_bounds__(256) void linear2_kernel(
    const void* __restrict__ inp,   // [RROWS, 32] f32 or fp16
    const float* __restrict__ W,    // [32, 32]
    const float* __restrict__ WU,   // [32, 32] = W@U precomputed
    __half* __restrict__ h16,       // [RROWS, 32] fp16
    __half* __restrict__ hu16)      // [RROWS, 32] fp16
{
    __shared__ float sx[64][33];
    int tid = threadIdx.x;
    int rowBase = blockIdx.x * 64;

    if (IN16) {
        // 64 rows x 64B = 4KB: one uint4 (8 halves) per thread
        const char* base = (const char*)inp + (size_t)rowBase * 64;
        uint4 v = *(const uint4*)(base + (size_t)tid * 16);
        float a[8];
        cvt8(v, a);
        int r = tid >> 2, q = tid & 3;
#pragma unroll
        for (int j = 0; j < 8; ++j) sx[r][q * 8 + j] = a[j];
    } else {
        const float4* in4 = (const float4*)((const float*)inp + (size_t)rowBase * CDIM);
#pragma unroll
        for (int i = 0; i < 2; ++i) {
            int idx = tid + i * 256;        // 0..511
            float4 v = in4[idx];
            int r = idx >> 3, q = idx & 7;
            sx[r][4 * q + 0] = v.x; sx[r][4 * q + 1] = v.y;
            sx[r][4 * q + 2] = v.z; sx[r][4 * q + 3] = v.w;
        }
    }
    __syncthreads();

    int lane  = tid & 63;
    int chunk = __builtin_amdgcn_readfirstlane(tid >> 6);   // 0..3, SGPR
    int row = rowBase + lane;

    float hr[8], acc[8];
#pragma unroll
    for (int j = 0; j < 8; ++j) { hr[j] = 0.f; acc[j] = 0.f; }

    const float* Wc  = W  + chunk * 8;      // uniform -> s_load
    const float* WUc = WU + chunk * 8;      // uniform -> s_load
#pragma unroll 4
    for (int k = 0; k < CDIM; ++k) {
        float xk = sx[lane][k];             // ds_read_b32
#pragma unroll
        for (int j = 0; j < 8; ++j) {
            hr[j]  = fmaf(xk, Wc[k * CDIM + j],  hr[j]);
            acc[j] = fmaf(xk, WUc[k * CDIM + j], acc[j]);
        }
    }

    uint4* hp = (uint4*)((char*)h16 + (size_t)row * 64 + chunk * 16);
    *hp = make_uint4(pk2(hr[0], hr[1]), pk2(hr[2], hr[3]),
                     pk2(hr[4], hr[5]), pk2(hr[6], hr[7]));

    uint4* up = (uint4*)((char*)hu16 + (size_t)row * 64 + chunk * 16);
    *up = make_uint4(pk2(acc[0], acc[1]), pk2(acc[2], acc[3]),
                     pk2(acc[4], acc[5]), pk2(acc[6], acc[7]));
}

// ---------------------------------------------------------------------------
// Aggregation: one wave per node, TWO edges per wave (R11 geometry).
// h is now fp16; OUT16 selects fp16 (layer-1 c1) vs f32 (layer-2 d_out) output.
// ---------------------------------------------------------------------------
template<bool OUT16>
__global__ __launch_bounds__(256) void agg_kernel(
    const int* __restrict__ offsets,
    const int* __restrict__ csr_src,
    const __half* __restrict__ hu16, // gather source [RROWS,32] fp16
    const __half* __restrict__ h16,  // [RROWS,32] fp16
    void* __restrict__ outp)         // fp16 [RROWS,32] or f32 [RROWS,32]
{
    int tid = threadIdx.x;
    int n = blockIdx.x * 4 + (tid >> 6);     // node for this wave
    int l64 = tid & 63;
    int half = l64 >> 5;                     // edge slot parity
    int l32 = l64 & 31;
    uint32_t rowOff = (uint32_t)l32 * 16u;   // byte off in 512B fp16 row
    const char* hub = (const char*)hu16;

    float b[8];
    cvt8(*(const uint4*)(hub + ((uint32_t)n << 9) + rowOff), b);  // x_i

    int k0 = offsets[n];
    int k1 = offsets[n + 1];

    float m[8];
#pragma unroll
    for (int j = 0; j < 8; ++j) m[j] = -INFINITY;

    int k = k0;
    int e0 = 0, e1 = 0;
    if (k + 4 <= k1) {
        e0 = csr_src[k + half];
        e1 = csr_src[k + 2 + half];
    }
    while (k + 4 <= k1) {
        uint4 r0 = *(const uint4*)(hub + (((uint32_t)e0 << 9) + rowOff));
        uint4 r1 = *(const uint4*)(hub + (((uint32_t)e1 << 9) + rowOff));
        k += 4;
        if (k + 4 <= k1) {                   // prefetch next indices
            e0 = csr_src[k + half];
            e1 = csr_src[k + 2 + half];
        }
        float a0[8], a1[8];
        cvt8(r0, a0); cvt8(r1, a1);
        float q0 = 0.f, q1 = 0.f;
#pragma unroll
        for (int j = 0; j < 8; ++j) { q0 = fmaf(a0[j], b[j], q0); q1 = fmaf(a1[j], b[j], q1); }
        q0 += __shfl_xor(q0, 1); q1 += __shfl_xor(q1, 1);
        q0 += __shfl_xor(q0, 2); q1 += __shfl_xor(q1, 2);
        float g0 = 1.f / (1.f + __expf(-q0));
        float g1 = 1.f / (1.f + __expf(-q1));
#pragma unroll
        for (int j = 0; j < 8; ++j) {
            m[j] = fmaxf(m[j], a0[j] * g0);
            m[j] = fmaxf(m[j], a1[j] * g1);
        }
    }
    // tail (<4 edges): both halves process the same edge (idempotent max)
    for (; k < k1; ++k) {
        int s = csr_src[k];
        float a0[8];
        cvt8(*(const uint4*)(hub + (((uint32_t)s << 9) + rowOff)), a0);
        float q0 = 0.f;
#pragma unroll
        for (int j = 0; j < 8; ++j) q0 = fmaf(a0[j], b[j], q0);
        q0 += __shfl_xor(q0, 1);
        q0 += __shfl_xor(q0, 2);
        float g0 = 1.f / (1.f + __expf(-q0));
#pragma unroll
        for (int j = 0; j < 8; ++j) m[j] = fmaxf(m[j], a0[j] * g0);
    }

    // combine the two halves' maxima
#pragma unroll
    for (int j = 0; j < 8; ++j) m[j] = fmaxf(m[j], __shfl_xor(m[j], 32));

    if (half == 0) {
        bool has = (k1 > k0);
        float hv[8];
        cvt8(*(const uint4*)((const char*)h16 + ((uint32_t)n << 9) + rowOff), hv);
        float o[8];
#pragma unroll
        for (int j = 0; j < 8; ++j) {
            float a = has ? m[j] : 0.f;
            float vv = hv[j] + a;
            o[j] = (vv >= 0.f) ? vv : 0.01f * vv;
        }
        if (OUT16) {
            uint4 w = make_uint4(pk2(o[0], o[1]), pk2(o[2], o[3]),
                                 pk2(o[4], o[5]), pk2(o[6], o[7]));
            *(uint4*)((char*)outp + ((uint32_t)n << 9) + rowOff) = w;
        } else {
            uint32_t nodeOff = (uint32_t)n * 1024u + (uint32_t)l32 * 32u;
            char* ob = (char*)outp;
            *(float4*)(ob + nodeOff)      = make_float4(o[0], o[1], o[2], o[3]);
            *(float4*)(ob + nodeOff + 16) = make_float4(o[4], o[5], o[6], o[7]);
        }
    }
}

// ---------------------------------------------------------------------------
// Orchestration: 8 dispatches (was 11).
// ws: [counts N][offsets N+1][cursor N][WU1 1024][WU2 1024][csr E][pad]
//     [A16 fp16][Hh fp16][HU fp16]  (~32 MB)
// Layer 1: linear2<f32>(X)->h1=Hh, hu1=HU;  agg<fp16>(HU,Hh)->c1=A16
// Layer 2: linear2<fp16>(A16)->h2=Hh, hu2=HU; agg<f32>(HU,Hh)->d_out
// ---------------------------------------------------------------------------
extern "C" void kernel_launch(void* const* d_in, const int* in_sizes, int n_in,
                              void* d_out, int out_size, void* d_ws, size_t ws_size,
                              hipStream_t stream)
{
    const float* X   = (const float*)d_in[0];
    const int*   ei  = (const int*)  d_in[1];
    // d_in[2]=edge_attr, d_in[4]=We1, d_in[7]=We2: dead code in reference
    const float* Wn1 = (const float*)d_in[3];
    const float* u1  = (const float*)d_in[5];
    const float* Wn2 = (const float*)d_in[6];
    const float* u2  = (const float*)d_in[8];

    int* counts  = (int*)d_ws;
    int* offsets = counts + NNODES;          // NNODES+1
    int* cursor  = offsets + NNODES + 1;
    float* WU1   = (float*)(cursor + NNODES); // 1024
    float* WU2   = WU1 + 1024;               // 1024
    int* csr     = (int*)(WU2 + 1024);       // NEDGES
    __half* A16  = (__half*)(((uintptr_t)(csr + NEDGES) + 255) & ~(uintptr_t)255);
    __half* Hh   = A16 + NELEM;              // h (both layers)
    __half* HU   = Hh + NELEM;               // hu (both layers)

    const int linBlocks  = RROWS / 64;             // 2500
    const int edgeBlocks = (NEDGES + 255) / 256;   // 1250
    const int aggBlocks  = NNODES / 4;             // 5000

    // ---- CSR + WU build: 4 dispatches ----
    init_kernel<<<NODEB + 8, 256, 0, stream>>>(Wn1, u1, WU1, Wn2, u2, WU2, counts);
    hist_kernel<<<edgeBlocks, 256, 0, stream>>>(ei, counts);
    scan_kernel<<<NODEB, 256, 0, stream>>>(counts, offsets, cursor);
    scatter_kernel<<<edgeBlocks, 256, 0, stream>>>(ei, cursor, csr);

    // ---- layer 1 ----
    linear2_kernel<false><<<linBlocks, 256, 0, stream>>>(X, Wn1, WU1, Hh, HU);
    agg_kernel<true><<<aggBlocks, 256, 0, stream>>>(offsets, csr, HU, Hh, A16);

    // ---- layer 2 ----
    linear2_kernel<true><<<linBlocks, 256, 0, stream>>>(A16, Wn2, WU2, Hh, HU);
    agg_kernel<false><<<aggBlocks, 256, 0, stream>>>(offsets, csr, HU, Hh, d_out);
}

// Round 14
// 138.732 us; speedup vs baseline: 1.7931x; 1.0450x over previous
//
#include <hip/hip_runtime.h>
#include <hip/hip_fp16.h>
#include <cstdint>
#include <cstddef>
#include <math.h>

// Problem constants (from reference)
#define NNODES 20000
#define NEDGES 320000
#define TDIM   8
#define CDIM   32
#define RROWS  (NNODES * TDIM)           // 160000 rows of 32 values (= 2500*64)
#define NELEM  (RROWS * CDIM)            // 5,120,000 elements
#define NODEB  79                        // ceil(NNODES/256)

static __device__ __forceinline__ unsigned pk2(float a, float b) {
    __half2 h = __floats2half2_rn(a, b);
    return *reinterpret_cast<unsigned*>(&h);
}

// convert 8 packed halves (uint4) to 8 floats
static __device__ __forceinline__ void cvt8(uint4 r, float* a) {
    float2 f;
    f = __half22float2(*reinterpret_cast<__half2*>(&r.x)); a[0] = f.x; a[1] = f.y;
    f = __half22float2(*reinterpret_cast<__half2*>(&r.y)); a[2] = f.x; a[3] = f.y;
    f = __half22float2(*reinterpret_cast<__half2*>(&r.z)); a[4] = f.x; a[5] = f.y;
    f = __half22float2(*reinterpret_cast<__half2*>(&r.w)); a[6] = f.x; a[7] = f.y;
}

// ---------------------------------------------------------------------------
// init: zero counts (blocks 0..78) + WU = W@U for both layers (blocks 79..86).
// ---------------------------------------------------------------------------
__global__ __launch_bounds__(256) void init_kernel(
    const float* __restrict__ Wn1, const float* __restrict__ u1, float* __restrict__ WU1,
    const float* __restrict__ Wn2, const float* __restrict__ u2, float* __restrict__ WU2,
    int* __restrict__ counts)
{
    int blk = blockIdx.x, tid = threadIdx.x;
    if (blk < NODEB) {
        int i = blk * 256 + tid;
        if (i < NNODES) counts[i] = 0;
        return;
    }
    int b = blk - NODEB;                 // 0..7
    const float* W  = (b < 4) ? Wn1 : Wn2;
    const float* U  = (b < 4) ? u1  : u2;
    float*       WU = (b < 4) ? WU1 : WU2;
    int idx = (b & 3) * 256 + tid;       // 0..1023
    int k = idx >> 5, c = idx & 31;
    float acc = 0.f;
#pragma unroll
    for (int j = 0; j < CDIM; ++j) acc = fmaf(W[k * CDIM + j], U[j * CDIM + c], acc);
    WU[idx] = acc;
}

__global__ __launch_bounds__(256) void hist_kernel(
    const int* __restrict__ ei, int* __restrict__ counts)
{
    int e = blockIdx.x * 256 + threadIdx.x;
    if (e < NEDGES) atomicAdd(&counts[ei[NEDGES + e]], 1);
}

// ---------------------------------------------------------------------------
// Single-dispatch scan: each block redundantly sums counts before its range
// (coalesced) then local-scans its 256 counts.
// ---------------------------------------------------------------------------
__global__ __launch_bounds__(256) void scan_kernel(
    const int* __restrict__ counts,
    int* __restrict__ offsets, int* __restrict__ cursor)
{
    __shared__ int sd[256];
    int blk = blockIdx.x, tid = threadIdx.x;

    int pre = 0;
    for (int i = tid; i < blk * 256; i += 256) pre += counts[i];
    sd[tid] = pre;
    __syncthreads();
#pragma unroll
    for (int off = 128; off > 0; off >>= 1) {
        if (tid < off) sd[tid] += sd[tid + off];
        __syncthreads();
    }
    int base = sd[0];
    __syncthreads();

    int i = blk * 256 + tid;
    int v = (i < NNODES) ? counts[i] : 0;
    sd[tid] = v;
    __syncthreads();
#pragma unroll
    for (int off = 1; off < 256; off <<= 1) {
        int t = (tid >= off) ? sd[tid - off] : 0;
        __syncthreads();
        sd[tid] += t;
        __syncthreads();
    }
    int excl = base + sd[tid] - v;
    if (i < NNODES) { offsets[i] = excl; cursor[i] = excl; }
    if (i == NNODES - 1) offsets[NNODES] = NEDGES;
}

__global__ __launch_bounds__(256) void scatter_kernel(
    const int* __restrict__ ei,
    int* __restrict__ cursor,
    int* __restrict__ csr_src)
{
    int e = blockIdx.x * 256 + threadIdx.x;
    if (e < NEDGES) {
        int t = ei[NEDGES + e];
        int pos = atomicAdd(&cursor[t], 1);
        csr_src[pos] = ei[e];
    }
}

// ---------------------------------------------------------------------------
// Layer-1 linear: h16 = half(X @ W) ; hu16 = half(X @ WU).  (R9 geometry.)
// ---------------------------------------------------------------------------
__global__ __launch_bounds__(256) void linear2_kernel(
    const float* __restrict__ in,   // [RROWS, 32] f32
    const float* __restrict__ W,
    const float* __restrict__ WU,
    __half* __restrict__ h16,
    __half* __restrict__ hu16)
{
    __shared__ float sx[64][33];
    int tid = threadIdx.x;
    int rowBase = blockIdx.x * 64;

    const float4* in4 = (const float4*)(in + (size_t)rowBase * CDIM);
#pragma unroll
    for (int i = 0; i < 2; ++i) {
        int idx = tid + i * 256;
        float4 v = in4[idx];
        int r = idx >> 3, q = idx & 7;
        sx[r][4 * q + 0] = v.x; sx[r][4 * q + 1] = v.y;
        sx[r][4 * q + 2] = v.z; sx[r][4 * q + 3] = v.w;
    }
    __syncthreads();

    int lane  = tid & 63;
    int chunk = __builtin_amdgcn_readfirstlane(tid >> 6);
    int row = rowBase + lane;

    float hr[8], acc[8];
#pragma unroll
    for (int j = 0; j < 8; ++j) { hr[j] = 0.f; acc[j] = 0.f; }

    const float* Wc  = W  + chunk * 8;
    const float* WUc = WU + chunk * 8;
#pragma unroll 4
    for (int k = 0; k < CDIM; ++k) {
        float xk = sx[lane][k];
#pragma unroll
        for (int j = 0; j < 8; ++j) {
            hr[j]  = fmaf(xk, Wc[k * CDIM + j],  hr[j]);
            acc[j] = fmaf(xk, WUc[k * CDIM + j], acc[j]);
        }
    }

    uint4* hp = (uint4*)((char*)h16 + (size_t)row * 64 + chunk * 16);
    *hp = make_uint4(pk2(hr[0], hr[1]), pk2(hr[2], hr[3]),
                     pk2(hr[4], hr[5]), pk2(hr[6], hr[7]));
    uint4* up = (uint4*)((char*)hu16 + (size_t)row * 64 + chunk * 16);
    *up = make_uint4(pk2(acc[0], acc[1]), pk2(acc[2], acc[3]),
                     pk2(acc[4], acc[5]), pk2(acc[6], acc[7]));
}

// ---------------------------------------------------------------------------
// FUSED agg(layer1) + linear(layer2): 512 threads = 8 waves = 8 nodes/block.
// Phase A (per wave = 1 node): R11 agg (2 edges/wave, uint4 gathers, 2-step
// shfl dot); c1 = leaky(h1+agg1) kept in f32 LDS [64][33] (never hits HBM).
// Phase B: wave w computes cols 4w..4w+4 of h2 = c1@W2 and hu2 = c1@WU2 for
// all 64 rows; weight chunk is wave-uniform -> s_load SGPR operands; xk via
// ds_read_b32 at [r][k] ((r+k)%32 banks -> 2-way, free).
// ---------------------------------------------------------------------------
__global__ __launch_bounds__(512) void aggfuse_kernel(
    const int* __restrict__ offsets,
    const int* __restrict__ csr_src,
    const __half* __restrict__ hu16, // hu1 [RROWS,32] fp16
    const __half* __restrict__ h16,  // h1  [RROWS,32] fp16
    const float* __restrict__ W2,    // [32,32]
    const float* __restrict__ WU2,   // [32,32]
    __half* __restrict__ h2_16,      // out h2  [RROWS,32] fp16
    __half* __restrict__ hu2_16)     // out hu2 [RROWS,32] fp16
{
    __shared__ float sc1[64][33];
    int tid = threadIdx.x;
    int wid = tid >> 6;                      // 0..7, node slot
    int n = blockIdx.x * 8 + wid;
    int l64 = tid & 63;
    int half = l64 >> 5;
    int l32 = l64 & 31;
    uint32_t rowOff = (uint32_t)l32 * 16u;
    const char* hub = (const char*)hu16;

    float b[8];
    cvt8(*(const uint4*)(hub + ((uint32_t)n << 9) + rowOff), b);

    int k0 = offsets[n];
    int k1 = offsets[n + 1];

    float m[8];
#pragma unroll
    for (int j = 0; j < 8; ++j) m[j] = -INFINITY;

    int k = k0;
    int e0 = 0, e1 = 0;
    if (k + 4 <= k1) {
        e0 = csr_src[k + half];
        e1 = csr_src[k + 2 + half];
    }
    while (k + 4 <= k1) {
        uint4 r0 = *(const uint4*)(hub + (((uint32_t)e0 << 9) + rowOff));
        uint4 r1 = *(const uint4*)(hub + (((uint32_t)e1 << 9) + rowOff));
        k += 4;
        if (k + 4 <= k1) {
            e0 = csr_src[k + half];
            e1 = csr_src[k + 2 + half];
        }
        float a0[8], a1[8];
        cvt8(r0, a0); cvt8(r1, a1);
        float q0 = 0.f, q1 = 0.f;
#pragma unroll
        for (int j = 0; j < 8; ++j) { q0 = fmaf(a0[j], b[j], q0); q1 = fmaf(a1[j], b[j], q1); }
        q0 += __shfl_xor(q0, 1); q1 += __shfl_xor(q1, 1);
        q0 += __shfl_xor(q0, 2); q1 += __shfl_xor(q1, 2);
        float g0 = 1.f / (1.f + __expf(-q0));
        float g1 = 1.f / (1.f + __expf(-q1));
#pragma unroll
        for (int j = 0; j < 8; ++j) {
            m[j] = fmaxf(m[j], a0[j] * g0);
            m[j] = fmaxf(m[j], a1[j] * g1);
        }
    }
    for (; k < k1; ++k) {
        int s = csr_src[k];
        float a0[8];
        cvt8(*(const uint4*)(hub + (((uint32_t)s << 9) + rowOff)), a0);
        float q0 = 0.f;
#pragma unroll
        for (int j = 0; j < 8; ++j) q0 = fmaf(a0[j], b[j], q0);
        q0 += __shfl_xor(q0, 1);
        q0 += __shfl_xor(q0, 2);
        float g0 = 1.f / (1.f + __expf(-q0));
#pragma unroll
        for (int j = 0; j < 8; ++j) m[j] = fmaxf(m[j], a0[j] * g0);
    }

#pragma unroll
    for (int j = 0; j < 8; ++j) m[j] = fmaxf(m[j], __shfl_xor(m[j], 32));

    if (half == 0) {
        bool has = (k1 > k0);
        float hv[8];
        cvt8(*(const uint4*)((const char*)h16 + ((uint32_t)n << 9) + rowOff), hv);
        int rloc = wid * 8 + (l32 >> 2);     // row within block (node-local tau)
        int cbase = (l32 & 3) * 8;
#pragma unroll
        for (int j = 0; j < 8; ++j) {
            float a = has ? m[j] : 0.f;
            float vv = hv[j] + a;
            sc1[rloc][cbase + j] = (vv >= 0.f) ? vv : 0.01f * vv;
        }
    }
    __syncthreads();

    // ---- phase B: h2/hu2 for the block's 64 rows ----
    int w = __builtin_amdgcn_readfirstlane(wid);   // 0..7, SGPR
    int r = l64;                                   // row 0..63
    float h2[4], a2[4];
#pragma unroll
    for (int j = 0; j < 4; ++j) { h2[j] = 0.f; a2[j] = 0.f; }

    const float* Wc = W2  + w * 4;       // uniform -> s_load
    const float* Uc = WU2 + w * 4;       // uniform -> s_load
#pragma unroll 4
    for (int kk = 0; kk < CDIM; ++kk) {
        float xk = sc1[r][kk];           // ds_read_b32, 2-way bank alias
#pragma unroll
        for (int j = 0; j < 4; ++j) {
            h2[j] = fmaf(xk, Wc[kk * CDIM + j], h2[j]);
            a2[j] = fmaf(xk, Uc[kk * CDIM + j], a2[j]);
        }
    }

    size_t rowg = (size_t)blockIdx.x * 64 + r;
    *(uint2*)((char*)h2_16  + rowg * 64 + w * 8) = make_uint2(pk2(h2[0], h2[1]), pk2(h2[2], h2[3]));
    *(uint2*)((char*)hu2_16 + rowg * 64 + w * 8) = make_uint2(pk2(a2[0], a2[1]), pk2(a2[2], a2[3]));
}

// ---------------------------------------------------------------------------
// Final aggregation (layer 2): R11/R12 geometry, writes f32 d_out.
// ---------------------------------------------------------------------------
__global__ __launch_bounds__(256) void agg_kernel(
    const int* __restrict__ offsets,
    const int* __restrict__ csr_src,
    const __half* __restrict__ hu16,
    const __half* __restrict__ h16,
    float* __restrict__ outp)
{
    int tid = threadIdx.x;
    int n = blockIdx.x * 4 + (tid >> 6);
    int l64 = tid & 63;
    int half = l64 >> 5;
    int l32 = l64 & 31;
    uint32_t rowOff = (uint32_t)l32 * 16u;
    const char* hub = (const char*)hu16;

    float b[8];
    cvt8(*(const uint4*)(hub + ((uint32_t)n << 9) + rowOff), b);

    int k0 = offsets[n];
    int k1 = offsets[n + 1];

    float m[8];
#pragma unroll
    for (int j = 0; j < 8; ++j) m[j] = -INFINITY;

    int k = k0;
    int e0 = 0, e1 = 0;
    if (k + 4 <= k1) {
        e0 = csr_src[k + half];
        e1 = csr_src[k + 2 + half];
    }
    while (k + 4 <= k1) {
        uint4 r0 = *(const uint4*)(hub + (((uint32_t)e0 << 9) + rowOff));
        uint4 r1 = *(const uint4*)(hub + (((uint32_t)e1 << 9) + rowOff));
        k += 4;
        if (k + 4 <= k1) {
            e0 = csr_src[k + half];
            e1 = csr_src[k + 2 + half];
        }
        float a0[8], a1[8];
        cvt8(r0, a0); cvt8(r1, a1);
        float q0 = 0.f, q1 = 0.f;
#pragma unroll
        for (int j = 0; j < 8; ++j) { q0 = fmaf(a0[j], b[j], q0); q1 = fmaf(a1[j], b[j], q1); }
        q0 += __shfl_xor(q0, 1); q1 += __shfl_xor(q1, 1);
        q0 += __shfl_xor(q0, 2); q1 += __shfl_xor(q1, 2);
        float g0 = 1.f / (1.f + __expf(-q0));
        float g1 = 1.f / (1.f + __expf(-q1));
#pragma unroll
        for (int j = 0; j < 8; ++j) {
            m[j] = fmaxf(m[j], a0[j] * g0);
            m[j] = fmaxf(m[j], a1[j] * g1);
        }
    }
    for (; k < k1; ++k) {
        int s = csr_src[k];
        float a0[8];
        cvt8(*(const uint4*)(hub + (((uint32_t)s << 9) + rowOff)), a0);
        float q0 = 0.f;
#pragma unroll
        for (int j = 0; j < 8; ++j) q0 = fmaf(a0[j], b[j], q0);
        q0 += __shfl_xor(q0, 1);
        q0 += __shfl_xor(q0, 2);
        float g0 = 1.f / (1.f + __expf(-q0));
#pragma unroll
        for (int j = 0; j < 8; ++j) m[j] = fmaxf(m[j], a0[j] * g0);
    }

#pragma unroll
    for (int j = 0; j < 8; ++j) m[j] = fmaxf(m[j], __shfl_xor(m[j], 32));

    if (half == 0) {
        bool has = (k1 > k0);
        float hv[8];
        cvt8(*(const uint4*)((const char*)h16 + ((uint32_t)n << 9) + rowOff), hv);
        float o[8];
#pragma unroll
        for (int j = 0; j < 8; ++j) {
            float a = has ? m[j] : 0.f;
            float vv = hv[j] + a;
            o[j] = (vv >= 0.f) ? vv : 0.01f * vv;
        }
        uint32_t nodeOff = (uint32_t)n * 1024u + (uint32_t)l32 * 32u;
        char* ob = (char*)outp;
        *(float4*)(ob + nodeOff)      = make_float4(o[0], o[1], o[2], o[3]);
        *(float4*)(ob + nodeOff + 16) = make_float4(o[4], o[5], o[6], o[7]);
    }
}

// ---------------------------------------------------------------------------
// Orchestration: 7 dispatches.
// ws: [counts N][offsets N+1][cursor N][WU1 1024][WU2 1024][csr E][pad]
//     [Hh1][HU1][Hh2][HU2] (fp16, 10.24MB each)
// L1: linear2(X)->Hh1,HU1
// fused: agg1(HU1,Hh1) -> c1 in LDS -> h2,hu2 -> Hh2,HU2
// L2: agg(HU2,Hh2) -> d_out (f32)
// ---------------------------------------------------------------------------
extern "C" void kernel_launch(void* const* d_in, const int* in_sizes, int n_in,
                              void* d_out, int out_size, void* d_ws, size_t ws_size,
                              hipStream_t stream)
{
    const float* X   = (const float*)d_in[0];
    const int*   ei  = (const int*)  d_in[1];
    // d_in[2]=edge_attr, d_in[4]=We1, d_in[7]=We2: dead code in reference
    const float* Wn1 = (const float*)d_in[3];
    const float* u1  = (const float*)d_in[5];
    const float* Wn2 = (const float*)d_in[6];
    const float* u2  = (const float*)d_in[8];

    int* counts  = (int*)d_ws;
    int* offsets = counts + NNODES;           // NNODES+1
    int* cursor  = offsets + NNODES + 1;
    float* WU1   = (float*)(cursor + NNODES); // 1024
    float* WU2   = WU1 + 1024;                // 1024
    int* csr     = (int*)(WU2 + 1024);        // NEDGES
    __half* Hh1  = (__half*)(((uintptr_t)(csr + NEDGES) + 255) & ~(uintptr_t)255);
    __half* HU1  = Hh1 + NELEM;
    __half* Hh2  = HU1 + NELEM;
    __half* HU2  = Hh2 + NELEM;

    const int linBlocks  = RROWS / 64;             // 2500
    const int edgeBlocks = (NEDGES + 255) / 256;   // 1250
    const int fuseBlocks = NNODES / 8;             // 2500
    const int aggBlocks  = NNODES / 4;             // 5000

    // ---- CSR + WU build ----
    init_kernel<<<NODEB + 8, 256, 0, stream>>>(Wn1, u1, WU1, Wn2, u2, WU2, counts);
    hist_kernel<<<edgeBlocks, 256, 0, stream>>>(ei, counts);
    scan_kernel<<<NODEB, 256, 0, stream>>>(counts, offsets, cursor);
    scatter_kernel<<<edgeBlocks, 256, 0, stream>>>(ei, cursor, csr);

    // ---- layer 1 linear ----
    linear2_kernel<<<linBlocks, 256, 0, stream>>>(X, Wn1, WU1, Hh1, HU1);

    // ---- fused agg1 + linear2-L2 ----
    aggfuse_kernel<<<fuseBlocks, 512, 0, stream>>>(offsets, csr, HU1, Hh1,
                                                   Wn2, WU2, Hh2, HU2);

    // ---- layer 2 agg -> output ----
    agg_kernel<<<aggBlocks, 256, 0, stream>>>(offsets, csr, HU2, Hh2, (float*)d_out);
}